// Round 5
// baseline (411.865 us; speedup 1.0000x reference)
//
#include <hip/hip_runtime.h>
#include <math.h>

// NeuralMemory on MI355X — R5: latency fix. Tall GEMMs: wave tile 32x64
// (32 AGPR acc), block 128x64, grid (4,256) => 4 blocks/CU (16 waves/CU),
// explicit register double-buffer of the 6 frag loads per K-step.
// Retrieved un-fused into two tall passes. rgemm: 512 blocks + padded-LDS
// transpose (stride 40 shorts => conflict-free-ish reads and writes).

#define NTOK 32768
#define NM ((size_t)NTOK * 256)
#define LRc 1e-3f
#define WDc 1e-2f
#define EPSc 1e-8f

typedef __attribute__((ext_vector_type(8))) short bf16x8;
typedef __attribute__((ext_vector_type(4))) float f32x4;

__device__ __forceinline__ float b2f(unsigned short u) {
    union { unsigned int i; float f; } c;
    c.i = ((unsigned int)u) << 16;
    return c.f;
}
__device__ __forceinline__ unsigned short f2b(float f) {
    union { float f; unsigned int i; } c;
    c.f = f;
    unsigned int i = c.i;
    return (unsigned short)((i + 0x7FFFu + ((i >> 16) & 1u)) >> 16);
}
__device__ __forceinline__ float sigm(float z) { return 1.f / (1.f + __expf(-z)); }
__device__ __forceinline__ float siluf(float z) { return z * sigm(z); }
__device__ __forceinline__ float dsiluf(float z) {
    float s = sigm(z);
    return s * (1.f + z * (1.f - s));
}

// ---------------------------------------------------------------------------
// Tall MFMA GEMM, register-direct, wave tile 32x64: C[M,256] = A @ B with
// Bt[n][k] = B[k][n]. Block = 4 waves stacked in rows (128x64 tile).
// Grid (4, M/128 [, z]).
// EPI 0: Cb = A@B (batched z)                                  projections
// EPI 1: z=acc+bias; Zout=z; Cb = A+silu(z)                    fwd layer 0
// EPI 5: z=acc+bias; h2=A+silu(z); dh=alr*(2/D)*(h2-V);        fwd layer 1 +
//        dz=dh*dsilu(z); Cb=dz; Rout=dh; gb += colsum(dz)       bwd elemwise
// EPI 2: dh1=acc+Rin; dz0=dh1*dsilu(Zin); Cb=dz0; gb+=colsum   bwd layer 0
// EPI 3: Cb = A + silu(acc+bias)                               retrieved L0
// EPI 4: Cf = A + silu(acc+bias)  (fp32 out)                   retrieved L1
// ---------------------------------------------------------------------------
template <int EPI>
__global__ __launch_bounds__(256, 4) void mgemm_k(
    const unsigned short* __restrict__ A, const unsigned short* __restrict__ Bt,
    const float* __restrict__ bias, const unsigned short* __restrict__ Rin,
    const unsigned short* __restrict__ Zin, const unsigned short* __restrict__ Vb,
    const float* __restrict__ alr, unsigned short* __restrict__ Cb,
    float* __restrict__ Cf, unsigned short* __restrict__ Zout,
    unsigned short* __restrict__ Rout, float* __restrict__ gb, size_t zcs) {
    Bt += (size_t)blockIdx.z * 65536;
    Cb += (size_t)blockIdx.z * zcs;
    const int n0 = blockIdx.x * 64, m0 = blockIdx.y * 128;
    const int tid = threadIdx.x, lane = tid & 63, wv = tid >> 6;
    const int fr = lane & 15, fk = (lane >> 4) * 8;

    const size_t base_a = (size_t)(m0 + wv * 32 + fr) * 256 + fk;
    const size_t base_b = (size_t)(n0 + fr) * 256 + fk;

    f32x4 acc[2][4];
#pragma unroll
    for (int s = 0; s < 2; s++)
#pragma unroll
        for (int t = 0; t < 4; t++) acc[s][t] = (f32x4){0.f, 0.f, 0.f, 0.f};

    bf16x8 af[2][2], bf[2][4];
#pragma unroll
    for (int s = 0; s < 2; s++)
        af[0][s] = *(const bf16x8*)(A + base_a + (size_t)s * 4096);
#pragma unroll
    for (int t = 0; t < 4; t++)
        bf[0][t] = *(const bf16x8*)(Bt + base_b + (size_t)t * 4096);

#pragma unroll
    for (int it = 0; it < 8; it++) {
        const int cur = it & 1, nxt = cur ^ 1;
        if (it < 7) {
            const int k1 = (it + 1) * 32;
#pragma unroll
            for (int s = 0; s < 2; s++)
                af[nxt][s] = *(const bf16x8*)(A + base_a + (size_t)s * 4096 + k1);
#pragma unroll
            for (int t = 0; t < 4; t++)
                bf[nxt][t] = *(const bf16x8*)(Bt + base_b + (size_t)t * 4096 + k1);
        }
#pragma unroll
        for (int s = 0; s < 2; s++)
#pragma unroll
            for (int t = 0; t < 4; t++)
                acc[s][t] = __builtin_amdgcn_mfma_f32_16x16x32_bf16(
                    af[cur][s], bf[cur][t], acc[s][t], 0, 0, 0);
    }

    const int r0 = (lane >> 4) * 4, cc = lane & 15;
    float csum[4] = {0.f, 0.f, 0.f, 0.f};
#pragma unroll
    for (int s = 0; s < 2; s++) {
        const int row0 = m0 + wv * 32 + s * 16 + r0;
#pragma unroll
        for (int t = 0; t < 4; t++) {
            const int gcol = n0 + t * 16 + cc;
            float bv = 0.f;
            if (EPI == 1 || EPI == 3 || EPI == 4 || EPI == 5) bv = bias[gcol];
            f32x4 c = acc[s][t];
#pragma unroll
            for (int r = 0; r < 4; r++) {
                const size_t off = (size_t)(row0 + r) * 256 + gcol;
                const float v = c[r];
                if (EPI == 0) {
                    Cb[off] = f2b(v);
                } else if (EPI == 1) {
                    float z = v + bv;
                    Zout[off] = f2b(z);
                    Cb[off] = f2b(b2f(A[off]) + siluf(z));
                } else if (EPI == 5) {
                    float z = v + bv;
                    float h2 = b2f(A[off]) + siluf(z);
                    float a = alr[row0 + r] * (2.f / 256.f);
                    float dh = a * (h2 - b2f(Vb[off]));
                    float dz = dh * dsiluf(z);
                    Cb[off] = f2b(dz);
                    Rout[off] = f2b(dh);
                    csum[t] += dz;
                } else if (EPI == 2) {
                    float dh1 = v + b2f(Rin[off]);
                    float dz0 = dh1 * dsiluf(b2f(Zin[off]));
                    Cb[off] = f2b(dz0);
                    csum[t] += dz0;
                } else if (EPI == 3) {
                    Cb[off] = f2b(b2f(A[off]) + siluf(v + bv));
                } else {
                    Cf[off] = b2f(A[off]) + siluf(v + bv);
                }
            }
        }
    }
    if (EPI == 5 || EPI == 2) {
#pragma unroll
        for (int t = 0; t < 4; t++) {
            float v = csum[t];
            v += __shfl_down(v, 32);
            v += __shfl_down(v, 16);
            if (lane < 16) atomicAdd(&gb[n0 + t * 16 + cc], v);
        }
    }
}

// ---------------------------------------------------------------------------
// Reduction GEMM with transpose-on-load: gW[l][i][j] = sum_t X[t][i] dz[t][j]
// from row-major X, dz. Grid (2,2,128): j0, i0, z (layer=z>>6, chunk=z&63 of
// 512 tokens). LDS tiles As[i][t] 128x32 with row stride 40 shorts (pad 8):
// transpose-write 8 banks wide, frag-read 2-way max. fp32 partials.
// ---------------------------------------------------------------------------
__global__ __launch_bounds__(256, 2) void rgemm_k(
    const unsigned short* __restrict__ Kb, const unsigned short* __restrict__ h1b,
    const unsigned short* __restrict__ dz0b,
    const unsigned short* __restrict__ dz1b, float* __restrict__ pbuf) {
    __shared__ unsigned short As[128 * 40];
    __shared__ unsigned short Bs[128 * 40];
    const int z = blockIdx.z, layer = z >> 6, zc = z & 63;
    const unsigned short* Ag = layer ? h1b : Kb;
    const unsigned short* Bg = layer ? dz1b : dz0b;
    const int t0 = zc * 512;
    const int j0 = blockIdx.x * 128, i0 = blockIdx.y * 128;
    const int tid = threadIdx.x, lane = tid & 63, wave = tid >> 6;
    const int wr = (wave >> 1) * 64, wc = (wave & 1) * 64;
    const int fr = lane & 15, fk = (lane >> 4) * 8;
    const int pt = (tid >> 4) * 2, pi = (tid & 15) * 8;

    f32x4 acc[4][4];
#pragma unroll
    for (int i = 0; i < 4; i++)
#pragma unroll
        for (int j = 0; j < 4; j++) acc[i][j] = (f32x4){0.f, 0.f, 0.f, 0.f};

    for (int tt = t0; tt < t0 + 512; tt += 32) {
        uint4 a0 = *(const uint4*)(Ag + (size_t)(tt + pt) * 256 + i0 + pi);
        uint4 a1 = *(const uint4*)(Ag + (size_t)(tt + pt + 1) * 256 + i0 + pi);
        uint4 b0 = *(const uint4*)(Bg + (size_t)(tt + pt) * 256 + j0 + pi);
        uint4 b1 = *(const uint4*)(Bg + (size_t)(tt + pt + 1) * 256 + j0 + pi);
        const unsigned int* aw0 = (const unsigned int*)&a0;
        const unsigned int* aw1 = (const unsigned int*)&a1;
        const unsigned int* bw0 = (const unsigned int*)&b0;
        const unsigned int* bw1 = (const unsigned int*)&b1;
#pragma unroll
        for (int ii = 0; ii < 8; ii++) {
            unsigned int alo = (aw0[ii >> 1] >> (16 * (ii & 1))) & 0xFFFFu;
            unsigned int ahi = (aw1[ii >> 1] >> (16 * (ii & 1))) & 0xFFFFu;
            unsigned int blo = (bw0[ii >> 1] >> (16 * (ii & 1))) & 0xFFFFu;
            unsigned int bhi = (bw1[ii >> 1] >> (16 * (ii & 1))) & 0xFFFFu;
            const int ad = ((pi + ii) * 40 + pt) >> 1;
            ((unsigned int*)As)[ad] = alo | (ahi << 16);
            ((unsigned int*)Bs)[ad] = blo | (bhi << 16);
        }
        __syncthreads();
        bf16x8 af[4], bfr[4];
#pragma unroll
        for (int i = 0; i < 4; i++) {
            af[i] = *(const bf16x8*)&As[(wr + i * 16 + fr) * 40 + fk];
            bfr[i] = *(const bf16x8*)&Bs[(wc + i * 16 + fr) * 40 + fk];
        }
#pragma unroll
        for (int i = 0; i < 4; i++)
#pragma unroll
            for (int j = 0; j < 4; j++)
                acc[i][j] = __builtin_amdgcn_mfma_f32_16x16x32_bf16(
                    af[i], bfr[j], acc[i][j], 0, 0, 0);
        __syncthreads();
    }

    float* P = pbuf + (size_t)((layer << 6) + zc) * 65536;
    const int r0 = (lane >> 4) * 4, cc = lane & 15;
#pragma unroll
    for (int mi = 0; mi < 4; mi++)
#pragma unroll
        for (int ni = 0; ni < 4; ni++) {
            f32x4 c = acc[mi][ni];
#pragma unroll
            for (int r = 0; r < 4; r++)
                P[(size_t)(i0 + wr + mi * 16 + r0 + r) * 256 +
                  (j0 + wc + ni * 16 + cc)] = c[r];
        }
}

__global__ void reduce_k(const float* __restrict__ pbuf, float* __restrict__ accW) {
    int idx = blockIdx.x * 256 + threadIdx.x;  // 131072
    int layer = idx >> 16, rc = idx & 65535;
    const float* p = pbuf + (size_t)layer * 64 * 65536 + rc;
    float s = 0.f;
#pragma unroll 8
    for (int c = 0; c < 64; c++) s += p[(size_t)c * 65536];
    accW[idx] = s;
}

// x fp32 -> xb bf16 + alr = 0.1*sigmoid(x@Wlr+blr), one wave per row
__global__ __launch_bounds__(256) void prep_k(const float* __restrict__ x,
                                              const float* __restrict__ Wlr,
                                              const float* __restrict__ blr,
                                              unsigned short* __restrict__ xb,
                                              float* __restrict__ alr) {
    const int wave = threadIdx.x >> 6, lane = threadIdx.x & 63;
    const int r = blockIdx.x * 4 + wave;
    float4 w = *(const float4*)(Wlr + lane * 4);
    float4 v = *(const float4*)(x + (size_t)r * 256 + lane * 4);
    float s = v.x * w.x + v.y * w.y + v.z * w.z + v.w * w.w;
    unsigned int p0 = (unsigned int)f2b(v.x) | ((unsigned int)f2b(v.y) << 16);
    unsigned int p1 = (unsigned int)f2b(v.z) | ((unsigned int)f2b(v.w) << 16);
    *(uint2*)(xb + (size_t)r * 256 + lane * 4) = make_uint2(p0, p1);
#pragma unroll
    for (int off = 32; off; off >>= 1) s += __shfl_down(s, off);
    if (lane == 0) alr[r] = 0.1f * sigm(s + blr[0]);
}

// weight prep: z=0..4 transpose+cvt {Wk,Wq,Wv,Ws0,Ws1}; z=5 straight cvt Ws1
__global__ void wprep_k(const float* __restrict__ Wk, const float* __restrict__ Wq,
                        const float* __restrict__ Wv, const float* __restrict__ Ws,
                        unsigned short* __restrict__ wt) {
    const int z = blockIdx.y;
    const int idx = blockIdx.x * 256 + threadIdx.x;  // 0..65535
    const float* src = z == 0 ? Wk : z == 1 ? Wq : z == 2 ? Wv
                     : z == 3 ? Ws : Ws + 65536;
    unsigned short* dst = wt + (size_t)z * 65536;
    float v = src[idx];
    if (z == 5)
        dst[idx] = f2b(v);
    else
        dst[(idx & 255) * 256 + (idx >> 8)] = f2b(v);
}

__global__ void adamw_w_k(const float* __restrict__ Ws,
                          const float* __restrict__ accW,
                          unsigned short* __restrict__ nWt,
                          float* __restrict__ outSW) {
    int idx = blockIdx.x * 256 + threadIdx.x;  // 131072
    float g = accW[idx];
    outSW[idx] = -g;
    float nw = Ws[idx] * (1.f - LRc * WDc) - LRc * g / (fabsf(g) + EPSc);
    int l = idx >> 16, k = (idx >> 8) & 255, n = idx & 255;
    nWt[(size_t)l * 65536 + n * 256 + k] = f2b(nw);
}

__global__ void adamw_b_k(const float* __restrict__ bs,
                          const float* __restrict__ accB,
                          float* __restrict__ nb, float* __restrict__ outSb) {
    int idx = blockIdx.x * 256 + threadIdx.x;  // 512
    float g = accB[idx];
    outSb[idx] = -g;
    nb[idx] = bs[idx] * (1.f - LRc * WDc) - LRc * g / (fabsf(g) + EPSc);
}

__global__ void zero_k(float* p, int n) {
    int i = blockIdx.x * 256 + threadIdx.x;
    if (i < n) p[i] = 0.f;
}

extern "C" void kernel_launch(void* const* d_in, const int* in_sizes, int n_in,
                              void* d_out, int out_size, void* d_ws,
                              size_t ws_size, hipStream_t stream) {
    const float* x = (const float*)d_in[0];
    const float* Wk = (const float*)d_in[1];
    const float* Wq = (const float*)d_in[2];
    const float* Wv = (const float*)d_in[3];
    const float* Wlr = (const float*)d_in[4];
    const float* blr = (const float*)d_in[5];
    const float* Ws = (const float*)d_in[6];
    const float* bs = (const float*)d_in[7];

    unsigned short* S = (unsigned short*)d_ws;
    unsigned short* xb = S + 0 * NM;  // dead after proj; reused as r1b
    unsigned short* Kb = S + 1 * NM;
    unsigned short* Qb = S + 2 * NM;
    unsigned short* Vb = S + 3 * NM;
    unsigned short* z0b = S + 4 * NM;
    unsigned short* h1b = S + 5 * NM;
    unsigned short* dz1b = S + 6 * NM;
    unsigned short* dh2b = S + 7 * NM;
    unsigned short* dz0b = S + 8 * NM;
    float* pbuf = (float*)(S + 9 * NM);  // 32 MB (slots 9-10)
    unsigned short* r1b = xb;

    unsigned short* wt = S + 11 * NM;
    unsigned short* W0t = wt + 3 * 65536;
    unsigned short* W1t = wt + 4 * 65536;
    unsigned short* W1b = wt + 5 * 65536;
    unsigned short* nW0t = wt + 6 * 65536;
    unsigned short* nW1t = wt + 7 * 65536;
    float* ft = (float*)(wt + 8 * 65536);
    float* alr = ft;              // 32768
    float* accW = ft + 32768;     // 131072
    float* accB = accW + 131072;  // 512
    float* nb = accB + 512;       // 512

    float* out_ret = (float*)d_out;
    float* out_sW = out_ret + NM;
    float* out_sb = out_sW + 131072;

    dim3 blk(256);
    dim3 g_tall(4, 256);

    zero_k<<<2, blk, 0, stream>>>(accB, 512);
    prep_k<<<8192, blk, 0, stream>>>(x, Wlr, blr, xb, alr);
    wprep_k<<<dim3(256, 6), blk, 0, stream>>>(Wk, Wq, Wv, Ws, wt);

    // projections K,Q,V (batched over z)
    mgemm_k<0><<<dim3(4, 256, 3), blk, 0, stream>>>(
        xb, wt, nullptr, nullptr, nullptr, nullptr, nullptr, Kb, nullptr,
        nullptr, nullptr, nullptr, NM);

    // fwd layer 0: h1 = K + silu(K@W0 + b0); saves z0
    mgemm_k<1><<<g_tall, blk, 0, stream>>>(Kb, W0t, bs, nullptr, nullptr,
                                           nullptr, nullptr, h1b, nullptr, z0b,
                                           nullptr, nullptr, 0);

    // fwd layer 1 + bwd elementwise (+ gb1 colsum fused)
    mgemm_k<5><<<g_tall, blk, 0, stream>>>(h1b, W1t, bs + 256, nullptr, nullptr,
                                           Vb, alr, dz1b, nullptr, nullptr,
                                           dh2b, accB + 256, 0);

    // bwd layer 0: dz0 = (dz1@W1^T + dh2) * dsilu(z0) (+ gb0 colsum fused)
    mgemm_k<2><<<g_tall, blk, 0, stream>>>(dz1b, W1b, nullptr, dh2b, z0b,
                                           nullptr, nullptr, dz0b, nullptr,
                                           nullptr, nullptr, accB, 0);

    // weight grads: transpose-on-load split-K partials + reduce
    rgemm_k<<<dim3(2, 2, 128), blk, 0, stream>>>(Kb, h1b, dz0b, dz1b, pbuf);
    reduce_k<<<512, blk, 0, stream>>>(pbuf, accW);

    // AdamW + surprises
    adamw_w_k<<<512, blk, 0, stream>>>(Ws, accW, nW0t, out_sW);
    adamw_b_k<<<2, blk, 0, stream>>>(bs, accB, nb, out_sb);

    // retrieved with new weights (two tall passes)
    mgemm_k<3><<<g_tall, blk, 0, stream>>>(Qb, nW0t, nb, nullptr, nullptr,
                                           nullptr, nullptr, r1b, nullptr,
                                           nullptr, nullptr, nullptr, 0);
    mgemm_k<4><<<g_tall, blk, 0, stream>>>(r1b, nW1t, nb + 256, nullptr,
                                           nullptr, nullptr, nullptr, nullptr,
                                           out_ret, nullptr, nullptr, nullptr,
                                           0);
}

// Round 6
// 322.415 us; speedup vs baseline: 1.2774x; 1.2774x over previous
//
#include <hip/hip_runtime.h>
#include <math.h>

// NeuralMemory on MI355X — R6: B-resident-LDS streaming tall GEMMs.
// B (256x256 bf16 = 128 KB) lives in LDS (row pad +8 => stride 264 shorts);
// one fill + one barrier, then waves stream A straight from global (frags are
// k-contiguous) with no further barriers. Block 512 thr = 8 waves =
// 4 m-stripes x 2 n-halves, wave tile 32x64, grid (2,256) => 2 blocks/CU.

#define NTOK 32768
#define NM ((size_t)NTOK * 256)
#define LRc 1e-3f
#define WDc 1e-2f
#define EPSc 1e-8f

typedef __attribute__((ext_vector_type(8))) short bf16x8;
typedef __attribute__((ext_vector_type(4))) float f32x4;

__device__ __forceinline__ float b2f(unsigned short u) {
    union { unsigned int i; float f; } c;
    c.i = ((unsigned int)u) << 16;
    return c.f;
}
__device__ __forceinline__ unsigned short f2b(float f) {
    union { float f; unsigned int i; } c;
    c.f = f;
    unsigned int i = c.i;
    return (unsigned short)((i + 0x7FFFu + ((i >> 16) & 1u)) >> 16);
}
__device__ __forceinline__ float sigm(float z) { return 1.f / (1.f + __expf(-z)); }
__device__ __forceinline__ float siluf(float z) { return z * sigm(z); }
__device__ __forceinline__ float dsiluf(float z) {
    float s = sigm(z);
    return s * (1.f + z * (1.f - s));
}

#define BSTRIDE 264  // 256 + 8 pad: row stride 528B = 132 dwords => 2-way max

// ---------------------------------------------------------------------------
// B-resident tall GEMM: C[M,256] = A[M,256] @ B, Bt[n][k] = B[k][n].
// Grid (2, M/128 [, z]); block 512 thr. Wave w: m-stripe (w>>2)... see below.
// EPI 0: Cb = A@B (batched z)                                  projections
// EPI 1: z=acc+bias; Zout=z; Cb = A+silu(z)                    fwd layer 0
// EPI 5: z=acc+bias; h2=A+silu(z); dh=alr*(2/D)*(h2-V);        fwd layer 1 +
//        dz=dh*dsilu(z); Cb=dz; Rout=dh; gb += colsum(dz)       bwd elemwise
// EPI 2: dh1=acc+Rin; dz0=dh1*dsilu(Zin); Cb=dz0; gb+=colsum   bwd layer 0
// EPI 3: Cb = A + silu(acc+bias)                               retrieved L0
// EPI 4: Cf = A + silu(acc+bias)  (fp32 out)                   retrieved L1
// ---------------------------------------------------------------------------
template <int EPI>
__global__ __launch_bounds__(512, 4) void wgemm_k(
    const unsigned short* __restrict__ A, const unsigned short* __restrict__ Bt,
    const float* __restrict__ bias, const unsigned short* __restrict__ Rin,
    const unsigned short* __restrict__ Zin, const unsigned short* __restrict__ Vb,
    const float* __restrict__ alr, unsigned short* __restrict__ Cb,
    float* __restrict__ Cf, unsigned short* __restrict__ Zout,
    unsigned short* __restrict__ Rout, float* __restrict__ gb, size_t zcs) {
    __shared__ unsigned short Bs[128 * BSTRIDE];
    Bt += (size_t)blockIdx.z * 65536;
    Cb += (size_t)blockIdx.z * zcs;
    const int n0 = blockIdx.x * 128, m0 = blockIdx.y * 128;
    const int tid = threadIdx.x, lane = tid & 63, wave = tid >> 6;

    // fill B tile (128 rows x 256 shorts) into LDS
#pragma unroll
    for (int it = 0; it < 8; it++) {
        int idx = it * 512 + tid;
        int row = idx >> 5, c8 = (idx & 31) * 8;
        *(uint4*)&Bs[row * BSTRIDE + c8] =
            *(const uint4*)(Bt + (size_t)(n0 + row) * 256 + c8);
    }
    __syncthreads();

    const int ms = wave >> 1, nh = wave & 1;
    const int wm0 = m0 + ms * 32;
    const int lnb = nh * 64, wn0 = n0 + lnb;
    const int fr = lane & 15, fk = (lane >> 4) * 8;

    f32x4 acc[2][4];
#pragma unroll
    for (int s = 0; s < 2; s++)
#pragma unroll
        for (int t = 0; t < 4; t++) acc[s][t] = (f32x4){0.f, 0.f, 0.f, 0.f};

    const size_t base_a = (size_t)(wm0 + fr) * 256 + fk;
#pragma unroll
    for (int it = 0; it < 8; it++) {
        const int k0 = it * 32;
        bf16x8 a0 = *(const bf16x8*)(A + base_a + k0);
        bf16x8 a1 = *(const bf16x8*)(A + base_a + 4096 + k0);
        bf16x8 bfr[4];
#pragma unroll
        for (int t = 0; t < 4; t++)
            bfr[t] = *(const bf16x8*)&Bs[(lnb + t * 16 + fr) * BSTRIDE + k0 + fk];
#pragma unroll
        for (int t = 0; t < 4; t++) {
            acc[0][t] = __builtin_amdgcn_mfma_f32_16x16x32_bf16(a0, bfr[t],
                                                                acc[0][t], 0, 0, 0);
            acc[1][t] = __builtin_amdgcn_mfma_f32_16x16x32_bf16(a1, bfr[t],
                                                                acc[1][t], 0, 0, 0);
        }
    }

    const int r0 = (lane >> 4) * 4, cc = lane & 15;
    float csum[4] = {0.f, 0.f, 0.f, 0.f};
#pragma unroll
    for (int s = 0; s < 2; s++) {
        const int row0 = wm0 + s * 16 + r0;
#pragma unroll
        for (int t = 0; t < 4; t++) {
            const int gcol = wn0 + t * 16 + cc;
            float bv = 0.f;
            if (EPI == 1 || EPI == 3 || EPI == 4 || EPI == 5) bv = bias[gcol];
            f32x4 c = acc[s][t];
#pragma unroll
            for (int r = 0; r < 4; r++) {
                const size_t off = (size_t)(row0 + r) * 256 + gcol;
                const float v = c[r];
                if (EPI == 0) {
                    Cb[off] = f2b(v);
                } else if (EPI == 1) {
                    float z = v + bv;
                    Zout[off] = f2b(z);
                    Cb[off] = f2b(b2f(A[off]) + siluf(z));
                } else if (EPI == 5) {
                    float z = v + bv;
                    float h2 = b2f(A[off]) + siluf(z);
                    float a = alr[row0 + r] * (2.f / 256.f);
                    float dh = a * (h2 - b2f(Vb[off]));
                    float dz = dh * dsiluf(z);
                    Cb[off] = f2b(dz);
                    Rout[off] = f2b(dh);
                    csum[t] += dz;
                } else if (EPI == 2) {
                    float dh1 = v + b2f(Rin[off]);
                    float dz0 = dh1 * dsiluf(b2f(Zin[off]));
                    Cb[off] = f2b(dz0);
                    csum[t] += dz0;
                } else if (EPI == 3) {
                    Cb[off] = f2b(b2f(A[off]) + siluf(v + bv));
                } else {
                    Cf[off] = b2f(A[off]) + siluf(v + bv);
                }
            }
        }
    }
    if (EPI == 5 || EPI == 2) {
#pragma unroll
        for (int t = 0; t < 4; t++) {
            float v = csum[t];
            v += __shfl_down(v, 32);
            v += __shfl_down(v, 16);
            if (lane < 16) atomicAdd(&gb[wn0 + t * 16 + cc], v);
        }
    }
}

// ---------------------------------------------------------------------------
// Reduction GEMM with transpose-on-load: gW[l][i][j] = sum_t X[t][i] dz[t][j]
// from row-major X, dz. Grid (2,2,128): j0, i0, z (layer=z>>6, chunk=z&63 of
// 512 tokens). LDS tiles 128x32 with row stride 40 shorts. fp32 partials.
// ---------------------------------------------------------------------------
__global__ __launch_bounds__(256, 2) void rgemm_k(
    const unsigned short* __restrict__ Kb, const unsigned short* __restrict__ h1b,
    const unsigned short* __restrict__ dz0b,
    const unsigned short* __restrict__ dz1b, float* __restrict__ pbuf) {
    __shared__ unsigned short As[128 * 40];
    __shared__ unsigned short Bs2[128 * 40];
    const int z = blockIdx.z, layer = z >> 6, zc = z & 63;
    const unsigned short* Ag = layer ? h1b : Kb;
    const unsigned short* Bg = layer ? dz1b : dz0b;
    const int t0 = zc * 512;
    const int j0 = blockIdx.x * 128, i0 = blockIdx.y * 128;
    const int tid = threadIdx.x, lane = tid & 63, wave = tid >> 6;
    const int wr = (wave >> 1) * 64, wc = (wave & 1) * 64;
    const int fr = lane & 15, fk = (lane >> 4) * 8;
    const int pt = (tid >> 4) * 2, pi = (tid & 15) * 8;

    f32x4 acc[4][4];
#pragma unroll
    for (int i = 0; i < 4; i++)
#pragma unroll
        for (int j = 0; j < 4; j++) acc[i][j] = (f32x4){0.f, 0.f, 0.f, 0.f};

    for (int tt = t0; tt < t0 + 512; tt += 32) {
        uint4 a0 = *(const uint4*)(Ag + (size_t)(tt + pt) * 256 + i0 + pi);
        uint4 a1 = *(const uint4*)(Ag + (size_t)(tt + pt + 1) * 256 + i0 + pi);
        uint4 b0 = *(const uint4*)(Bg + (size_t)(tt + pt) * 256 + j0 + pi);
        uint4 b1 = *(const uint4*)(Bg + (size_t)(tt + pt + 1) * 256 + j0 + pi);
        const unsigned int* aw0 = (const unsigned int*)&a0;
        const unsigned int* aw1 = (const unsigned int*)&a1;
        const unsigned int* bw0 = (const unsigned int*)&b0;
        const unsigned int* bw1 = (const unsigned int*)&b1;
#pragma unroll
        for (int ii = 0; ii < 8; ii++) {
            unsigned int alo = (aw0[ii >> 1] >> (16 * (ii & 1))) & 0xFFFFu;
            unsigned int ahi = (aw1[ii >> 1] >> (16 * (ii & 1))) & 0xFFFFu;
            unsigned int blo = (bw0[ii >> 1] >> (16 * (ii & 1))) & 0xFFFFu;
            unsigned int bhi = (bw1[ii >> 1] >> (16 * (ii & 1))) & 0xFFFFu;
            const int ad = ((pi + ii) * 40 + pt) >> 1;
            ((unsigned int*)As)[ad] = alo | (ahi << 16);
            ((unsigned int*)Bs2)[ad] = blo | (bhi << 16);
        }
        __syncthreads();
        bf16x8 af[4], bfr[4];
#pragma unroll
        for (int i = 0; i < 4; i++) {
            af[i] = *(const bf16x8*)&As[(wr + i * 16 + fr) * 40 + fk];
            bfr[i] = *(const bf16x8*)&Bs2[(wc + i * 16 + fr) * 40 + fk];
        }
#pragma unroll
        for (int i = 0; i < 4; i++)
#pragma unroll
            for (int j = 0; j < 4; j++)
                acc[i][j] = __builtin_amdgcn_mfma_f32_16x16x32_bf16(
                    af[i], bfr[j], acc[i][j], 0, 0, 0);
        __syncthreads();
    }

    float* P = pbuf + (size_t)((layer << 6) + zc) * 65536;
    const int r0 = (lane >> 4) * 4, cc = lane & 15;
#pragma unroll
    for (int mi = 0; mi < 4; mi++)
#pragma unroll
        for (int ni = 0; ni < 4; ni++) {
            f32x4 c = acc[mi][ni];
#pragma unroll
            for (int r = 0; r < 4; r++)
                P[(size_t)(i0 + wr + mi * 16 + r0 + r) * 256 +
                  (j0 + wc + ni * 16 + cc)] = c[r];
        }
}

__global__ void reduce_k(const float* __restrict__ pbuf, float* __restrict__ accW) {
    int idx = blockIdx.x * 256 + threadIdx.x;  // 131072
    int layer = idx >> 16, rc = idx & 65535;
    const float* p = pbuf + (size_t)layer * 64 * 65536 + rc;
    float s = 0.f;
#pragma unroll 8
    for (int c = 0; c < 64; c++) s += p[(size_t)c * 65536];
    accW[idx] = s;
}

// x fp32 -> xb bf16 + alr = 0.1*sigmoid(x@Wlr+blr), one wave per row
__global__ __launch_bounds__(256) void prep_k(const float* __restrict__ x,
                                              const float* __restrict__ Wlr,
                                              const float* __restrict__ blr,
                                              unsigned short* __restrict__ xb,
                                              float* __restrict__ alr) {
    const int wave = threadIdx.x >> 6, lane = threadIdx.x & 63;
    const int r = blockIdx.x * 4 + wave;
    float4 w = *(const float4*)(Wlr + lane * 4);
    float4 v = *(const float4*)(x + (size_t)r * 256 + lane * 4);
    float s = v.x * w.x + v.y * w.y + v.z * w.z + v.w * w.w;
    unsigned int p0 = (unsigned int)f2b(v.x) | ((unsigned int)f2b(v.y) << 16);
    unsigned int p1 = (unsigned int)f2b(v.z) | ((unsigned int)f2b(v.w) << 16);
    *(uint2*)(xb + (size_t)r * 256 + lane * 4) = make_uint2(p0, p1);
#pragma unroll
    for (int off = 32; off; off >>= 1) s += __shfl_down(s, off);
    if (lane == 0) alr[r] = 0.1f * sigm(s + blr[0]);
}

// weight prep: z=0..4 transpose+cvt {Wk,Wq,Wv,Ws0,Ws1}; z=5 straight cvt Ws1
__global__ void wprep_k(const float* __restrict__ Wk, const float* __restrict__ Wq,
                        const float* __restrict__ Wv, const float* __restrict__ Ws,
                        unsigned short* __restrict__ wt) {
    const int z = blockIdx.y;
    const int idx = blockIdx.x * 256 + threadIdx.x;  // 0..65535
    const float* src = z == 0 ? Wk : z == 1 ? Wq : z == 2 ? Wv
                     : z == 3 ? Ws : Ws + 65536;
    unsigned short* dst = wt + (size_t)z * 65536;
    float v = src[idx];
    if (z == 5)
        dst[idx] = f2b(v);
    else
        dst[(idx & 255) * 256 + (idx >> 8)] = f2b(v);
}

__global__ void adamw_w_k(const float* __restrict__ Ws,
                          const float* __restrict__ accW,
                          unsigned short* __restrict__ nWt,
                          float* __restrict__ outSW) {
    int idx = blockIdx.x * 256 + threadIdx.x;  // 131072
    float g = accW[idx];
    outSW[idx] = -g;
    float nw = Ws[idx] * (1.f - LRc * WDc) - LRc * g / (fabsf(g) + EPSc);
    int l = idx >> 16, k = (idx >> 8) & 255, n = idx & 255;
    nWt[(size_t)l * 65536 + n * 256 + k] = f2b(nw);
}

__global__ void adamw_b_k(const float* __restrict__ bs,
                          const float* __restrict__ accB,
                          float* __restrict__ nb, float* __restrict__ outSb) {
    int idx = blockIdx.x * 256 + threadIdx.x;  // 512
    float g = accB[idx];
    outSb[idx] = -g;
    nb[idx] = bs[idx] * (1.f - LRc * WDc) - LRc * g / (fabsf(g) + EPSc);
}

__global__ void zero_k(float* p, int n) {
    int i = blockIdx.x * 256 + threadIdx.x;
    if (i < n) p[i] = 0.f;
}

extern "C" void kernel_launch(void* const* d_in, const int* in_sizes, int n_in,
                              void* d_out, int out_size, void* d_ws,
                              size_t ws_size, hipStream_t stream) {
    const float* x = (const float*)d_in[0];
    const float* Wk = (const float*)d_in[1];
    const float* Wq = (const float*)d_in[2];
    const float* Wv = (const float*)d_in[3];
    const float* Wlr = (const float*)d_in[4];
    const float* blr = (const float*)d_in[5];
    const float* Ws = (const float*)d_in[6];
    const float* bs = (const float*)d_in[7];

    unsigned short* S = (unsigned short*)d_ws;
    unsigned short* xb = S + 0 * NM;  // dead after proj; reused as r1b
    unsigned short* Kb = S + 1 * NM;
    unsigned short* Qb = S + 2 * NM;
    unsigned short* Vb = S + 3 * NM;
    unsigned short* z0b = S + 4 * NM;
    unsigned short* h1b = S + 5 * NM;
    unsigned short* dz1b = S + 6 * NM;
    unsigned short* dh2b = S + 7 * NM;
    unsigned short* dz0b = S + 8 * NM;
    float* pbuf = (float*)(S + 9 * NM);  // 32 MB (slots 9-10)
    unsigned short* r1b = xb;

    unsigned short* wt = S + 11 * NM;
    unsigned short* W0t = wt + 3 * 65536;
    unsigned short* W1t = wt + 4 * 65536;
    unsigned short* W1b = wt + 5 * 65536;
    unsigned short* nW0t = wt + 6 * 65536;
    unsigned short* nW1t = wt + 7 * 65536;
    float* ft = (float*)(wt + 8 * 65536);
    float* alr = ft;              // 32768
    float* accW = ft + 32768;     // 131072
    float* accB = accW + 131072;  // 512
    float* nb = accB + 512;       // 512

    float* out_ret = (float*)d_out;
    float* out_sW = out_ret + NM;
    float* out_sb = out_sW + 131072;

    dim3 blk5(512);
    dim3 blk(256);
    dim3 g_tall(2, 256);

    zero_k<<<2, blk, 0, stream>>>(accB, 512);
    prep_k<<<8192, blk, 0, stream>>>(x, Wlr, blr, xb, alr);
    wprep_k<<<dim3(256, 6), blk, 0, stream>>>(Wk, Wq, Wv, Ws, wt);

    // projections K,Q,V (batched over z)
    wgemm_k<0><<<dim3(2, 256, 3), blk5, 0, stream>>>(
        xb, wt, nullptr, nullptr, nullptr, nullptr, nullptr, Kb, nullptr,
        nullptr, nullptr, nullptr, NM);

    // fwd layer 0: h1 = K + silu(K@W0 + b0); saves z0
    wgemm_k<1><<<g_tall, blk5, 0, stream>>>(Kb, W0t, bs, nullptr, nullptr,
                                            nullptr, nullptr, h1b, nullptr,
                                            z0b, nullptr, nullptr, 0);

    // fwd layer 1 + bwd elementwise (+ gb1 colsum fused)
    wgemm_k<5><<<g_tall, blk5, 0, stream>>>(h1b, W1t, bs + 256, nullptr,
                                            nullptr, Vb, alr, dz1b, nullptr,
                                            nullptr, dh2b, accB + 256, 0);

    // bwd layer 0: dz0 = (dz1@W1^T + dh2) * dsilu(z0) (+ gb0 colsum fused)
    wgemm_k<2><<<g_tall, blk5, 0, stream>>>(dz1b, W1b, nullptr, dh2b, z0b,
                                            nullptr, nullptr, dz0b, nullptr,
                                            nullptr, nullptr, accB, 0);

    // weight grads: transpose-on-load split-K partials + reduce
    rgemm_k<<<dim3(2, 2, 128), blk, 0, stream>>>(Kb, h1b, dz0b, dz1b, pbuf);
    reduce_k<<<512, blk, 0, stream>>>(pbuf, accW);

    // AdamW + surprises
    adamw_w_k<<<512, blk, 0, stream>>>(Ws, accW, nW0t, out_sW);
    adamw_b_k<<<2, blk, 0, stream>>>(bs, accB, nb, out_sb);

    // retrieved with new weights (two tall passes)
    wgemm_k<3><<<g_tall, blk5, 0, stream>>>(Qb, nW0t, nb, nullptr, nullptr,
                                            nullptr, nullptr, r1b, nullptr,
                                            nullptr, nullptr, nullptr, 0);
    wgemm_k<4><<<g_tall, blk5, 0, stream>>>(r1b, nW1t, nb + 256, nullptr,
                                            nullptr, nullptr, nullptr, nullptr,
                                            out_ret, nullptr, nullptr, nullptr,
                                            0);
}